// Round 1
// baseline (42.776 us; speedup 1.0000x reference)
//
#include <hip/hip_runtime.h>

// N=200000, D=256, S=64
// out[i][j] = sqrt((x[i]^2) . exp(10*w_log_var)) * z[j] + x[i] . w_mu
//
// One 64-lane wave per row:
//   lane l holds x[i, 4l..4l+3] (float4), w_mu fragment, exp-weight fragment.
//   Butterfly shfl_xor reduces mean & var partials; lane j writes out[i][j].

#define D_DIM 256
#define S_DIM 64

__global__ __launch_bounds__(256) void reparam_rows_kernel(
    const float* __restrict__ x,
    const float* __restrict__ w_mu,
    const float* __restrict__ w_log_var,
    const float* __restrict__ z,
    float* __restrict__ out,
    int n_rows)
{
    const int lane = threadIdx.x & 63;
    const int wave_in_block = threadIdx.x >> 6;
    const int waves_per_block = blockDim.x >> 6;
    const int global_wave = blockIdx.x * waves_per_block + wave_in_block;
    const int total_waves = gridDim.x * waves_per_block;

    // Per-lane constants (uniform across the grid-stride loop).
    const float4 wm = *reinterpret_cast<const float4*>(w_mu + lane * 4);
    const float4 wl = *reinterpret_cast<const float4*>(w_log_var + lane * 4);
    float4 ew;
    ew.x = expf(10.0f * wl.x);
    ew.y = expf(10.0f * wl.y);
    ew.z = expf(10.0f * wl.z);
    ew.w = expf(10.0f * wl.w);
    const float zl = z[lane];  // S == 64 == wave width

    for (int i = global_wave; i < n_rows; i += total_waves) {
        const float4 v = *reinterpret_cast<const float4*>(x + (size_t)i * D_DIM + lane * 4);

        float m = v.x * wm.x + v.y * wm.y + v.z * wm.z + v.w * wm.w;
        float s = (v.x * v.x) * ew.x + (v.y * v.y) * ew.y
                + (v.z * v.z) * ew.z + (v.w * v.w) * ew.w;

        // 64-lane butterfly reduction of both sums.
        #pragma unroll
        for (int off = 32; off > 0; off >>= 1) {
            m += __shfl_xor(m, off);
            s += __shfl_xor(s, off);
        }

        out[(size_t)i * S_DIM + lane] = sqrtf(s) * zl + m;
    }
}

extern "C" void kernel_launch(void* const* d_in, const int* in_sizes, int n_in,
                              void* d_out, int out_size, void* d_ws, size_t ws_size,
                              hipStream_t stream) {
    const float* x         = (const float*)d_in[0];
    const float* w_mu      = (const float*)d_in[1];
    const float* w_log_var = (const float*)d_in[2];
    const float* z         = (const float*)d_in[3];
    float* out = (float*)d_out;

    const int n_rows = in_sizes[0] / D_DIM;  // 200000

    const int block = 256;                    // 4 waves/block
    const int waves_per_block = block / 64;
    int grid = (n_rows + waves_per_block - 1) / waves_per_block;
    if (grid > 2048) grid = 2048;             // 8192 waves = 32/CU, grid-stride rest

    reparam_rows_kernel<<<grid, block, 0, stream>>>(x, w_mu, w_log_var, z, out, n_rows);
}